// Round 1
// baseline (255.367 us; speedup 1.0000x reference)
//
#include <hip/hip_runtime.h>

// mRNN: B=128, C=64, H=32, T=256. Bidirectional per-channel RNN.
// Decomposition: chain = (c, dir, b), 16384 chains. 8 lanes per chain,
// each lane owns 4 rows of the 32-row state and its 4x32 slice of W in VGPRs.
// State exchanged per step via a 128B LDS tile per chain (wave-synchronous,
// no barriers: all 8 lanes of a chain are consecutive lanes of one wave).
constexpr int Bn = 128, Cn = 64, Hn = 32, Tn = 256;

__global__ __launch_bounds__(256, 2)
void mrnn_scan(const float* __restrict__ x, const float* __restrict__ m,
               const float* __restrict__ d,
               const float* __restrict__ Wf, const float* __restrict__ Vf,
               const float* __restrict__ cf,
               const float* __restrict__ Wb, const float* __restrict__ Vb,
               const float* __restrict__ cb,
               const float* __restrict__ U,
               float* __restrict__ pf_out, float* __restrict__ pb_out) {
  // bid = dir*256 + c*4 + g   (g = batch group of 32)
  const int bid = blockIdx.x;
  const int dir = bid >> 8;
  const int c   = (bid >> 2) & (Cn - 1);
  const int g   = bid & 3;
  const int tid = threadIdx.x;
  const int chain = tid >> 3;   // 0..31 within block
  const int r     = tid & 7;    // row group: rows [r*4, r*4+4)
  const int b = g * 32 + chain;

  const float* W  = dir ? Wb : Wf;
  const float* V  = dir ? Vb : Vf;
  const float* cc = dir ? cb : cf;

  // Per-thread weights (live in VGPRs for the whole T loop)
  float4 w[4][8];
  float  vv[4][3], bias[4], uu[4];
#pragma unroll
  for (int rr = 0; rr < 4; ++rr) {
    const int row = r * 4 + rr;
    const float* wp = W + (c * Hn + row) * Hn;
#pragma unroll
    for (int k4 = 0; k4 < 8; ++k4) w[rr][k4] = ((const float4*)wp)[k4];
    const float* vp = V + (c * Hn + row) * 3;
    vv[rr][0] = vp[0]; vv[rr][1] = vp[1]; vv[rr][2] = vp[2];
    bias[rr] = cc[c * Hn + row];
    uu[rr]   = U[c * (2 * Hn) + dir * Hn + row];
  }

  // LDS hidden state: 32 chains * stride 36 floats (pad +4 -> bank rotation)
  __shared__ __align__(16) float hbuf[32 * 36];
  float* hc = &hbuf[chain * 36];
  *(float4*)&hc[r * 4] = make_float4(0.f, 0.f, 0.f, 0.f);  // h0 = 0

  const long bc = (long)(b * Cn + c) * Tn;
  const float* px = x + bc;
  const float* pm = m + bc;
  const float* pd = d + bc;
  float* pout = (dir ? pb_out : pf_out) + bc;

  // forward step t reads orig index max(t-1,0); backward step s reads
  // orig index (s==0 ? T-1 : T-s).  Prefetch one step ahead.
  const int src0 = dir ? (Tn - 1) : 0;
  float xv = px[src0], mv = pm[src0], dv = pd[src0];

  for (int t = 0; t < Tn; ++t) {
    // source index for step t+1 (always in range; last one unused)
    const int srcn = dir ? (Tn - 1 - t) : t;
    const float nx = px[srcn], nm = pm[srcn], nd = pd[srcn];

    // read full 32-wide state of this chain (broadcast across the 8 lanes)
    float4 h[8];
#pragma unroll
    for (int j = 0; j < 8; ++j) h[j] = *(const float4*)&hc[j * 4];

    float acc[4];
#pragma unroll
    for (int rr = 0; rr < 4; ++rr)
      acc[rr] = fmaf(vv[rr][0], xv, fmaf(vv[rr][1], mv, fmaf(vv[rr][2], dv, bias[rr])));

#pragma unroll
    for (int k4 = 0; k4 < 8; ++k4) {
#pragma unroll
      for (int rr = 0; rr < 4; ++rr) {
        acc[rr] = fmaf(w[rr][k4].x, h[k4].x, acc[rr]);
        acc[rr] = fmaf(w[rr][k4].y, h[k4].y, acc[rr]);
        acc[rr] = fmaf(w[rr][k4].z, h[k4].z, acc[rr]);
        acc[rr] = fmaf(w[rr][k4].w, h[k4].w, acc[rr]);
      }
    }
#pragma unroll
    for (int rr = 0; rr < 4; ++rr) acc[rr] = fmaxf(acc[rr], 0.f);

    // partial projection U . h_new over own 4 rows, reduce across 8 lanes
    float p = fmaf(uu[0], acc[0], fmaf(uu[1], acc[1],
              fmaf(uu[2], acc[2], uu[3] * acc[3])));
    p += __shfl_xor(p, 1, 8);
    p += __shfl_xor(p, 2, 8);
    p += __shfl_xor(p, 4, 8);
    if (r == 0) pout[t] = p;

    // publish new state (in-order DS pipe + lockstep wave => no barrier)
    *(float4*)&hc[r * 4] = make_float4(acc[0], acc[1], acc[2], acc[3]);

    xv = nx; mv = nm; dv = nd;
  }
}

// out[b,c,t] = relu(pf[b,c,t] + pb[b,c,T-1-t] + c0[c]); pf staged in d_out.
__global__ __launch_bounds__(256)
void mrnn_combine(const float* __restrict__ pb, const float* __restrict__ c0,
                  float* __restrict__ out) {
  const int idx = blockIdx.x * 256 + threadIdx.x;
  const int t  = idx & (Tn - 1);
  const int bc = idx >> 8;            // Tn == 256
  const int c  = bc & (Cn - 1);
  const float v = out[idx] + pb[(bc << 8) + (Tn - 1 - t)] + c0[c];
  out[idx] = fmaxf(v, 0.f);
}

extern "C" void kernel_launch(void* const* d_in, const int* in_sizes, int n_in,
                              void* d_out, int out_size, void* d_ws, size_t ws_size,
                              hipStream_t stream) {
  const float* x  = (const float*)d_in[0];
  const float* m  = (const float*)d_in[1];
  const float* dd = (const float*)d_in[2];
  const float* Wf = (const float*)d_in[3];
  const float* Vf = (const float*)d_in[4];
  const float* cf = (const float*)d_in[5];
  const float* Wb = (const float*)d_in[6];
  const float* Vb = (const float*)d_in[7];
  const float* cb = (const float*)d_in[8];
  const float* U  = (const float*)d_in[9];
  const float* c0 = (const float*)d_in[10];
  float* out = (float*)d_out;
  float* pb  = (float*)d_ws;   // C*B*T floats = 8 MB scratch

  mrnn_scan<<<512, 256, 0, stream>>>(x, m, dd, Wf, Vf, cf, Wb, Vb, cb, U, out, pb);
  mrnn_combine<<<(Bn * Cn * Tn) / 256, 256, 0, stream>>>(pb, c0, out);
}

// Round 2
// 232.971 us; speedup vs baseline: 1.0961x; 1.0961x over previous
//
#include <hip/hip_runtime.h>

// mRNN: B=128, C=64, H=32, T=256. Bidirectional per-channel RNN.
// chain = (c, dir, b): 16384 chains. 8 lanes per chain, 4 rows each.
// Weights pinned into VGPRs via empty asm (compiler at -O3 otherwise sinks
// the loop-invariant loads into the t-loop: round-1 showed VGPR_Count=92,
// impossible with the 128-float weight slice resident).
// State exchanged per step via a 128B LDS tile per chain, wave-synchronous
// (all 8 lanes of a chain are in one wave; DS pipe is in-order per wave).
constexpr int Bn = 128, Cn = 64, Hn = 32, Tn = 256;

#define PIN(v) asm volatile("" : "+v"(v))

__global__ __launch_bounds__(256, 2)
void mrnn_scan(const float* __restrict__ x, const float* __restrict__ m,
               const float* __restrict__ d,
               const float* __restrict__ Wf, const float* __restrict__ Vf,
               const float* __restrict__ cf,
               const float* __restrict__ Wb, const float* __restrict__ Vb,
               const float* __restrict__ cb,
               const float* __restrict__ U,
               float* __restrict__ pf_out, float* __restrict__ pb_out) {
  const int bid = blockIdx.x;
  const int dir = bid >> 8;
  const int c   = (bid >> 2) & (Cn - 1);
  const int g   = bid & 3;
  const int tid = threadIdx.x;
  const int chain = tid >> 3;   // 0..31 within block
  const int r     = tid & 7;    // rows [r*4, r*4+4)
  const int b = g * 32 + chain;

  const float* W  = dir ? Wb : Wf;
  const float* V  = dir ? Vb : Vf;
  const float* cc = dir ? cb : cf;

  float4 w[4][8];
  float  vv[4][3], bias[4], uu[4];
#pragma unroll
  for (int rr = 0; rr < 4; ++rr) {
    const int row = r * 4 + rr;
    const float* wp = W + (c * Hn + row) * Hn;
#pragma unroll
    for (int k4 = 0; k4 < 8; ++k4) w[rr][k4] = ((const float4*)wp)[k4];
    const float* vp = V + (c * Hn + row) * 3;
    vv[rr][0] = vp[0]; vv[rr][1] = vp[1]; vv[rr][2] = vp[2];
    bias[rr] = cc[c * Hn + row];
    uu[rr]   = U[c * (2 * Hn) + dir * Hn + row];
  }
  // Pin everything loop-invariant into VGPRs (opaque defs: no remat/reload).
#pragma unroll
  for (int rr = 0; rr < 4; ++rr) {
#pragma unroll
    for (int k4 = 0; k4 < 8; ++k4) {
      PIN(w[rr][k4].x); PIN(w[rr][k4].y); PIN(w[rr][k4].z); PIN(w[rr][k4].w);
    }
    PIN(vv[rr][0]); PIN(vv[rr][1]); PIN(vv[rr][2]); PIN(bias[rr]); PIN(uu[rr]);
  }

  // LDS hidden state: 32 chains * stride 36 floats (pad -> bank rotation)
  __shared__ __align__(16) float hbuf[32 * 36];
  float* hc = &hbuf[chain * 36];
  *(float4*)&hc[r * 4] = make_float4(0.f, 0.f, 0.f, 0.f);

  const long bc = (long)(b * Cn + c) * Tn;
  const float* px = x + bc;
  const float* pm = m + bc;
  const float* pd = d + bc;
  float* pout = (dir ? pb_out : pf_out) + bc;

  // input schedule: forward step t uses x[max(t-1,0)];
  // backward step s uses x[s==0 ? T-1 : T-s]. Backward writes pre-reversed.
  float cx = dir ? px[Tn - 1] : px[0];
  float cm = dir ? pm[Tn - 1] : pm[0];
  float cd = dir ? pd[Tn - 1] : pd[0];

  for (int t0 = 0; t0 < Tn; t0 += 4) {
    const int qoff = dir ? (Tn - 4 - t0) : t0;
    const float4 qx = *(const float4*)(px + qoff);
    const float4 qm = *(const float4*)(pm + qoff);
    const float4 qd = *(const float4*)(pd + qoff);
    float inx[4], inm[4], ind[4];
    if (!dir) {
      inx[0] = cx; inx[1] = qx.x; inx[2] = qx.y; inx[3] = qx.z; cx = qx.w;
      inm[0] = cm; inm[1] = qm.x; inm[2] = qm.y; inm[3] = qm.z; cm = qm.w;
      ind[0] = cd; ind[1] = qd.x; ind[2] = qd.y; ind[3] = qd.z; cd = qd.w;
    } else {
      inx[0] = cx; inx[1] = qx.w; inx[2] = qx.z; inx[3] = qx.y; cx = qx.x;
      inm[0] = cm; inm[1] = qm.w; inm[2] = qm.z; inm[3] = qm.y; cm = qm.x;
      ind[0] = cd; ind[1] = qd.w; ind[2] = qd.z; ind[3] = qd.y; cd = qd.x;
    }

#pragma unroll
    for (int u = 0; u < 4; ++u) {
      const int t = t0 + u;
      float4 h[8];
#pragma unroll
      for (int j = 0; j < 8; ++j) h[j] = *(const float4*)&hc[j * 4];

      float acc[4];
#pragma unroll
      for (int rr = 0; rr < 4; ++rr)
        acc[rr] = fmaf(vv[rr][0], inx[u],
                  fmaf(vv[rr][1], inm[u],
                  fmaf(vv[rr][2], ind[u], bias[rr])));

#pragma unroll
      for (int k4 = 0; k4 < 8; ++k4) {
#pragma unroll
        for (int rr = 0; rr < 4; ++rr) {
          acc[rr] = fmaf(w[rr][k4].x, h[k4].x, acc[rr]);
          acc[rr] = fmaf(w[rr][k4].y, h[k4].y, acc[rr]);
          acc[rr] = fmaf(w[rr][k4].z, h[k4].z, acc[rr]);
          acc[rr] = fmaf(w[rr][k4].w, h[k4].w, acc[rr]);
        }
      }
#pragma unroll
      for (int rr = 0; rr < 4; ++rr) acc[rr] = fmaxf(acc[rr], 0.f);

      float p = fmaf(uu[0], acc[0], fmaf(uu[1], acc[1],
                fmaf(uu[2], acc[2], uu[3] * acc[3])));
      p += __shfl_xor(p, 1, 8);
      p += __shfl_xor(p, 2, 8);
      p += __shfl_xor(p, 4, 8);
      if (r == 0) pout[dir ? (Tn - 1 - t) : t] = p;

      *(float4*)&hc[r * 4] = make_float4(acc[0], acc[1], acc[2], acc[3]);
    }
  }
}

// out[i] = relu(pf[i] + pb[i] + c0[c]); pf staged in d_out, pb pre-reversed.
__global__ __launch_bounds__(256)
void mrnn_combine(const float* __restrict__ pb, const float* __restrict__ c0,
                  float* __restrict__ out) {
  const int i4 = blockIdx.x * 256 + threadIdx.x;
  const int c = (i4 >> 6) & (Cn - 1);          // (i4*4 >> 8) & 63
  const float c0v = c0[c];
  float4 a = ((const float4*)out)[i4];
  const float4 b = ((const float4*)pb)[i4];
  a.x = fmaxf(a.x + b.x + c0v, 0.f);
  a.y = fmaxf(a.y + b.y + c0v, 0.f);
  a.z = fmaxf(a.z + b.z + c0v, 0.f);
  a.w = fmaxf(a.w + b.w + c0v, 0.f);
  ((float4*)out)[i4] = a;
}

extern "C" void kernel_launch(void* const* d_in, const int* in_sizes, int n_in,
                              void* d_out, int out_size, void* d_ws, size_t ws_size,
                              hipStream_t stream) {
  const float* x  = (const float*)d_in[0];
  const float* m  = (const float*)d_in[1];
  const float* dd = (const float*)d_in[2];
  const float* Wf = (const float*)d_in[3];
  const float* Vf = (const float*)d_in[4];
  const float* cf = (const float*)d_in[5];
  const float* Wb = (const float*)d_in[6];
  const float* Vb = (const float*)d_in[7];
  const float* cb = (const float*)d_in[8];
  const float* U  = (const float*)d_in[9];
  const float* c0 = (const float*)d_in[10];
  float* out = (float*)d_out;
  float* pb  = (float*)d_ws;   // B*C*T floats = 8 MB scratch

  mrnn_scan<<<512, 256, 0, stream>>>(x, m, dd, Wf, Vf, cf, Wb, Vb, cb, U, out, pb);
  mrnn_combine<<<(Bn * Cn * Tn) / (256 * 4), 256, 0, stream>>>(pb, c0, out);
}

// Round 3
// 165.924 us; speedup vs baseline: 1.5391x; 1.4041x over previous
//
#include <hip/hip_runtime.h>

// mRNN B=128, C=64, H=32, T=256 via MFMA 16x16x32 bf16 with split-bf16
// (hi+lo) precision. One wave per (dir, c, batch-group-of-16): 1024 waves.
//
// Layout-closed recurrence: h stored as the B-operand fragment
// (B[k=8q+j][n=lane&15], q=lane>>4). Two 16x16 D tiles cover the 32 rows,
// with a row PERMUTATION chosen so lane (q,n)'s C/D values
// (row=4q+reg, col=n; m89-verified layout) are exactly h[8q..8q+7][n] —
// the lane's own next-step B fragment. tile0 = physical rows with bit2=0
// (rho0(l)=8*(l>>2)+(l&3)), tile1 = bit2=1. W rows / V / bias / U are
// loaded pre-permuted, so no LDS and no cross-lane exchange per step.
//
// Precision: W = W_hi + W_lo, h = h_hi + h_lo (truncation splits);
// D = W_hi@h_hi + W_hi@h_lo + W_lo@h_hi + (V-term, fp32). Missing
// lo@lo term ~2^-16 relative per step -> negligible vs 2% threshold.
constexpr int Bn = 128, Cn = 64, Hn = 32, Tn = 256;

typedef __attribute__((ext_vector_type(8))) short short8;
typedef __attribute__((ext_vector_type(4))) float f32x4;

__device__ __forceinline__ void split_bf16(float f, short& hi, short& lo) {
  unsigned u = __float_as_uint(f);
  hi = (short)(u >> 16);                       // truncated bf16
  float r = f - __uint_as_float(u & 0xffff0000u);  // exact residual
  lo = (short)(__float_as_uint(r) >> 16);
}

__global__ __launch_bounds__(64)
void mrnn_scan(const float* __restrict__ x, const float* __restrict__ m,
               const float* __restrict__ d,
               const float* __restrict__ Wf, const float* __restrict__ Vf,
               const float* __restrict__ cf,
               const float* __restrict__ Wb, const float* __restrict__ Vb,
               const float* __restrict__ cb,
               const float* __restrict__ U,
               float* __restrict__ pf_out, float* __restrict__ pb_out) {
  const int bid = blockIdx.x;
  const int dir = bid >> 9;                 // 0 fwd, 1 bwd
  const int c   = (bid >> 3) & (Cn - 1);
  const int g   = bid & 7;                  // batch group of 16
  const int tid = threadIdx.x;              // 0..63, one wave
  const int q = tid >> 4;
  const int n = tid & 15;
  const int b = g * 16 + n;

  const float* W  = dir ? Wb : Wf;
  const float* V  = dir ? Vb : Vf;
  const float* cc = dir ? cb : cf;

  // ---- A fragments: A[m=lane&15][k=8q+j]; tile row perm rho0(m)=8*(m>>2)+(m&3)
  const int ra0 = 8 * (n >> 2) + (n & 3);   // tile0 physical row for A-row m=n
  const int ra1 = ra0 + 4;                  // tile1
  short8 A0h, A0l, A1h, A1l;
#pragma unroll
  for (int j = 0; j < 8; ++j) {
    const float w0 = W[(c * Hn + ra0) * Hn + 8 * q + j];
    const float w1 = W[(c * Hn + ra1) * Hn + 8 * q + j];
    short hi, lo;
    split_bf16(w0, hi, lo); A0h[j] = hi; A0l[j] = lo;
    split_bf16(w1, hi, lo); A1h[j] = hi; A1l[j] = lo;
  }

  // ---- per-lane D rows: tile0 -> physical 8q+r, tile1 -> 8q+4+r (r=0..3)
  float v0x[4], v0y[4], v0z[4], bs0[4], uu0[4];
  float v1x[4], v1y[4], v1z[4], bs1[4], uu1[4];
#pragma unroll
  for (int r = 0; r < 4; ++r) {
    const int row0 = 8 * q + r, row1 = row0 + 4;
    const float* vp0 = V + (c * Hn + row0) * 3;
    v0x[r] = vp0[0]; v0y[r] = vp0[1]; v0z[r] = vp0[2];
    bs0[r] = cc[c * Hn + row0];
    uu0[r] = U[c * 2 * Hn + dir * Hn + row0];
    const float* vp1 = V + (c * Hn + row1) * 3;
    v1x[r] = vp1[0]; v1y[r] = vp1[1]; v1z[r] = vp1[2];
    bs1[r] = cc[c * Hn + row1];
    uu1[r] = U[c * 2 * Hn + dir * Hn + row1];
  }

  // ---- state: B fragments (h = 0)
  short8 Bh = {0, 0, 0, 0, 0, 0, 0, 0};
  short8 Bl = {0, 0, 0, 0, 0, 0, 0, 0};

  const long base = ((long)b * Cn + c) * Tn;
  const float* px = x + base;
  const float* pm = m + base;
  const float* pd = d + base;
  float* pout = (dir ? pb_out : pf_out) + base;

  // input schedule (round-2-verified): fwd step t reads idx max(t-1,0);
  // bwd step s reads idx min(T-s, T-1). Carry + aligned-quad prefetch.
  float cx, cm2, cd2;
  f32x4 qx, qm, qd;
  if (!dir) {
    cx = px[0]; cm2 = pm[0]; cd2 = pd[0];
    qx = *(const f32x4*)px; qm = *(const f32x4*)pm; qd = *(const f32x4*)pd;
  } else {
    cx = px[Tn - 1]; cm2 = pm[Tn - 1]; cd2 = pd[Tn - 1];
    qx = *(const f32x4*)(px + Tn - 4);
    qm = *(const f32x4*)(pm + Tn - 4);
    qd = *(const f32x4*)(pd + Tn - 4);
  }

  for (int t0 = 0; t0 < Tn; t0 += 4) {
    // prefetch next quad (clamped; last one unused)
    int qn_ = dir ? (Tn - 8 - t0) : (t0 + 4);
    if (qn_ < 0) qn_ = 0;
    if (qn_ > Tn - 4) qn_ = Tn - 4;
    const f32x4 nqx = *(const f32x4*)(px + qn_);
    const f32x4 nqm = *(const f32x4*)(pm + qn_);
    const f32x4 nqd = *(const f32x4*)(pd + qn_);

    float inx[4], inm[4], ind[4];
    if (!dir) {
      inx[0] = cx;  inx[1] = qx.x; inx[2] = qx.y; inx[3] = qx.z; cx  = qx.w;
      inm[0] = cm2; inm[1] = qm.x; inm[2] = qm.y; inm[3] = qm.z; cm2 = qm.w;
      ind[0] = cd2; ind[1] = qd.x; ind[2] = qd.y; ind[3] = qd.z; cd2 = qd.w;
    } else {
      inx[0] = cx;  inx[1] = qx.w; inx[2] = qx.z; inx[3] = qx.y; cx  = qx.x;
      inm[0] = cm2; inm[1] = qm.w; inm[2] = qm.z; inm[3] = qm.y; cm2 = qm.x;
      ind[0] = cd2; ind[1] = qd.w; ind[2] = qd.z; ind[3] = qd.y; cd2 = qd.x;
    }

    f32x4 pacc;
#pragma unroll
    for (int u = 0; u < 4; ++u) {
      const float ix = inx[u], im = inm[u], idv = ind[u];
      // acc init = V-term + bias (fp32 exact)
      f32x4 acc0, acc1;
#pragma unroll
      for (int r = 0; r < 4; ++r) {
        acc0[r] = fmaf(v0x[r], ix, fmaf(v0y[r], im, fmaf(v0z[r], idv, bs0[r])));
        acc1[r] = fmaf(v1x[r], ix, fmaf(v1y[r], im, fmaf(v1z[r], idv, bs1[r])));
      }
      // W@h via 3 split products per tile
      acc0 = __builtin_amdgcn_mfma_f32_16x16x32_bf16(A0l, Bh, acc0, 0, 0, 0);
      acc1 = __builtin_amdgcn_mfma_f32_16x16x32_bf16(A1l, Bh, acc1, 0, 0, 0);
      acc0 = __builtin_amdgcn_mfma_f32_16x16x32_bf16(A0h, Bl, acc0, 0, 0, 0);
      acc1 = __builtin_amdgcn_mfma_f32_16x16x32_bf16(A1h, Bl, acc1, 0, 0, 0);
      acc0 = __builtin_amdgcn_mfma_f32_16x16x32_bf16(A0h, Bh, acc0, 0, 0, 0);
      acc1 = __builtin_amdgcn_mfma_f32_16x16x32_bf16(A1h, Bh, acc1, 0, 0, 0);
      // relu
#pragma unroll
      for (int r = 0; r < 4; ++r) {
        acc0[r] = fmaxf(acc0[r], 0.f);
        acc1[r] = fmaxf(acc1[r], 0.f);
      }
      // U partial over this lane's 8 physical rows, reduce over q-lanes
      float p = uu0[0] * acc0[0];
      p = fmaf(uu0[1], acc0[1], p); p = fmaf(uu0[2], acc0[2], p);
      p = fmaf(uu0[3], acc0[3], p);
      p = fmaf(uu1[0], acc1[0], p); p = fmaf(uu1[1], acc1[1], p);
      p = fmaf(uu1[2], acc1[2], p); p = fmaf(uu1[3], acc1[3], p);
      p += __shfl_xor(p, 16);
      p += __shfl_xor(p, 32);
      pacc[dir ? (3 - u) : u] = p;
      // rebuild B fragments: lane (q,n) holds exactly h[8q..8q+7][n]
#pragma unroll
      for (int r = 0; r < 4; ++r) {
        short hi, lo;
        split_bf16(acc0[r], hi, lo); Bh[r] = hi;     Bl[r] = lo;
        split_bf16(acc1[r], hi, lo); Bh[4 + r] = hi; Bl[4 + r] = lo;
      }
    }
    if (q == 0) {
      if (!dir) *(f32x4*)(pout + t0) = pacc;
      else      *(f32x4*)(pout + (Tn - 4 - t0)) = pacc;  // pre-reversed
    }
    qx = nqx; qm = nqm; qd = nqd;
  }
}

// out[i] = relu(pf[i] + pb[i] + c0[c]); pf staged in d_out, pb pre-reversed.
__global__ __launch_bounds__(256)
void mrnn_combine(const float* __restrict__ pb, const float* __restrict__ c0,
                  float* __restrict__ out) {
  const int i4 = blockIdx.x * 256 + threadIdx.x;
  const int c = (i4 >> 6) & (Cn - 1);
  const float c0v = c0[c];
  float4 a = ((const float4*)out)[i4];
  const float4 bb = ((const float4*)pb)[i4];
  a.x = fmaxf(a.x + bb.x + c0v, 0.f);
  a.y = fmaxf(a.y + bb.y + c0v, 0.f);
  a.z = fmaxf(a.z + bb.z + c0v, 0.f);
  a.w = fmaxf(a.w + bb.w + c0v, 0.f);
  ((float4*)out)[i4] = a;
}

extern "C" void kernel_launch(void* const* d_in, const int* in_sizes, int n_in,
                              void* d_out, int out_size, void* d_ws, size_t ws_size,
                              hipStream_t stream) {
  const float* x  = (const float*)d_in[0];
  const float* m  = (const float*)d_in[1];
  const float* dd = (const float*)d_in[2];
  const float* Wf = (const float*)d_in[3];
  const float* Vf = (const float*)d_in[4];
  const float* cf = (const float*)d_in[5];
  const float* Wb = (const float*)d_in[6];
  const float* Vb = (const float*)d_in[7];
  const float* cb = (const float*)d_in[8];
  const float* U  = (const float*)d_in[9];
  const float* c0 = (const float*)d_in[10];
  float* out = (float*)d_out;
  float* pb  = (float*)d_ws;   // B*C*T floats = 8 MB scratch

  mrnn_scan<<<1024, 64, 0, stream>>>(x, m, dd, Wf, Vf, cf, Wb, Vb, cb, U, out, pb);
  mrnn_combine<<<(Bn * Cn * Tn) / (256 * 4), 256, 0, stream>>>(pb, c0, out);
}